// Round 7
// baseline (352.865 us; speedup 1.0000x reference)
//
#include <hip/hip_runtime.h>

typedef _Float16 half_t;
typedef _Float16 half8 __attribute__((ext_vector_type(8)));
typedef float f32x4 __attribute__((ext_vector_type(4)));

#define D_EMBED   1024
#define D_CROSS   768
#define N_HEADS   8
#define D_HEAD    128
#define BATCH     8
#define SEQ_Q     4096
#define SEQ_KV    77
#define M_Q       (BATCH*SEQ_Q)     /* 32768 */
#define ROWS_KV   (BATCH*SEQ_KV)    /* 616   */
#define ROWS_KV_PAD 640

// ---------------- workspace layout (bytes) ----------------
#define WS_Q     ((size_t)0)                                  // q (swizzled fp16), attn-out in place
#define WS_WQT   (WS_Q    + (size_t)M_Q*D_EMBED*2)            // Wq^T fp16 [1024][1024] swizzled
#define WS_WOT   (WS_WQT  + (size_t)D_EMBED*D_EMBED*2)        // Wo^T fp16 [1024][1024] swizzled
#define WS_WKVT  (WS_WOT  + (size_t)D_EMBED*D_EMBED*2)        // [Wk;Wv]^T fp16 [2048][768] plain
#define WS_YH    (WS_WKVT + (size_t)2*D_EMBED*D_CROSS*2)      // y fp16 padded [640][768]
#define WS_KV    (WS_YH   + (size_t)ROWS_KV_PAD*D_CROSS*2)    // kv fp16 [640][2048] plain
#define WS_BKV   (WS_KV   + (size_t)ROWS_KV_PAD*2*D_EMBED*2)  // bias concat fp32 [2048]

__device__ __forceinline__ void gload_lds16(const void* g, void* lds) {
  __builtin_amdgcn_global_load_lds(
      (const __attribute__((address_space(1))) unsigned int*)g,
      (__attribute__((address_space(3))) unsigned int*)lds, 16, 0, 0);
}
// raw barrier + scheduler fence (no vmcnt/lgkm drain — that's the whole point)
__device__ __forceinline__ void BAR() {
  __builtin_amdgcn_s_barrier();
  __builtin_amdgcn_sched_barrier(0);
}

// ---------------- prep kernels ----------------
// dst[n][k] = (half) src[k][n]; SWZ: XOR byte bits[5:4] with (n>>1)&3 (LDS bank swizzle baked in)
template<bool SWZ>
__global__ void transpose_f32f16(const float* __restrict__ src, half_t* __restrict__ dst,
                                 int K, int N) {
  __shared__ float tile[32][33];
  int n0 = blockIdx.x * 32, k0 = blockIdx.y * 32;
  int tx = threadIdx.x, ty = threadIdx.y;
#pragma unroll
  for (int j = 0; j < 4; ++j)
    tile[ty + j*8][tx] = src[(size_t)(k0 + ty + j*8)*N + n0 + tx];
  __syncthreads();
#pragma unroll
  for (int j = 0; j < 4; ++j) {
    int n = n0 + ty + j*8, k = k0 + tx;
    size_t byte = ((size_t)n*K + k)*2;
    if (SWZ) byte ^= ((size_t)((n>>1)&3))<<4;
    *(half_t*)((char*)dst + byte) = (half_t)tile[tx][ty + j*8];
  }
}

__global__ void convert_pad_y(const float* __restrict__ y, half_t* __restrict__ yh) {
  int idx = blockIdx.x * 256 + threadIdx.x;
  int s = idx / D_CROSS;
  yh[idx] = (s < ROWS_KV) ? (half_t)y[idx] : (half_t)0.f;
}

__global__ void concat_bias(const float* __restrict__ bk, const float* __restrict__ bv,
                            float* __restrict__ bkv) {
  int i = blockIdx.x * 256 + threadIdx.x;
  bkv[i] = (i < D_EMBED) ? bk[i] : bv[i - D_EMBED];
}

// ---------------- GEMM: C[M,N] = A[M,K] * Bt[N,K]^T + bias[N] ----------------
// 128x128 tile, BK=32, 256 thr (4 waves), wave tile 64x64 — R2-verified body.
// T4: raw s_barrier + COUNTED vmcnt — loads stay in flight across barriers.
// fp16 path: A staged 2-ahead (3-buf, L3 latency), B 1-ahead (2-buf,
// L2-resident weights). Issue B-then-A so end-of-iter vmcnt(2) forces
// {A(t+1),B(t+1)} landed (oldest-first) and leaves A(t+2) flying.
// AF32 path: A reg-staged (loads early, cvt+swizzled ds_write after compute;
// the ds_write's data-dependence implicitly waits vmcnt down past B(t+1));
// B staged 2-ahead (3-buf); lgkmcnt(0) before barrier for ds_write visibility.
// SWZ: XCD panel remap (gridDim.x==8) + LDS bank swizzle via pre-swizzled
// globals (byte^=((row>>1)&3)<<4), linear staging, XOR'd ds accesses.
template<bool AF32, bool OUTF32, bool SWZ>
__global__ __launch_bounds__(256, 3)
void gemm_f16(const void* __restrict__ Av, const half_t* __restrict__ Bt,
              const float* __restrict__ bias, void* __restrict__ Cv,
              int M, int N, int K) {
  __shared__ half_t As[AF32 ? 2 : 3][128*32];   // 8 KB per buf
  __shared__ half_t Bs[AF32 ? 3 : 2][128*32];   // total 40 KB -> 4 blocks/CU
  const int tid = threadIdx.x;
  const int l  = tid & 63;
  const int w  = tid >> 6;
  const int l4 = l & 15, lh = l >> 4;

  int bx, by;
  if constexpr (SWZ) {
    const int s = blockIdx.x + (blockIdx.y << 3);
    bx = (s >> 3) & 7;
    by = (s & 7) + ((s >> 6) << 3);
  } else {
    bx = blockIdx.x; by = blockIdx.y;
  }
  const int bn0 = bx * 128;
  const int bm0 = by * 128;
  const int wr = w >> 1, wc = w & 1;
  const int skey = SWZ ? ((l4 >> 1) & 3) : 0;
  const int rslot = (lh ^ skey) << 4;      // byte offset of 16B slot within 64B row

  f32x4 acc[4][4] = {};
  const int nk = K >> 5;

  // staging address pieces (constant across iters)
  const int srow = w*16 + (l >> 2);        // 0..63
  const int scol = (l & 3)*8;              // half-elem col within 32
  const size_t bgoff0 = (size_t)(bn0 + srow)*K + scol;
  const size_t bgoff1 = (size_t)(bn0 + 64 + srow)*K + scol;

  auto stageB = [&](int kt, int bb) {
    gload_lds16(Bt + bgoff0 + kt*32, (char*)Bs[bb] + w*1024);
    gload_lds16(Bt + bgoff1 + kt*32, (char*)Bs[bb] + 4096 + w*1024);
  };
  auto stageA16 = [&](int kt, int bb) {
    const half_t* A = (const half_t*)Av;
    gload_lds16(A + (size_t)(bm0 + srow)*K + scol + kt*32,      (char*)As[bb] + w*1024);
    gload_lds16(A + (size_t)(bm0 + 64 + srow)*K + scol + kt*32, (char*)As[bb] + 4096 + w*1024);
  };

  // AF32 reg staging: row = tid>>2 (0..63), 8 floats/thread/row-half
  f32x4 L0, L1, L2, L3;                     // 16 VGPR in flight
  const int arow = tid >> 2;
  const int ac0  = (tid & 3) * 8;
  const int wslot = SWZ ? (((tid & 3) ^ ((tid >> 3) & 3)) << 4)   // key=(arow>>1)&3=(tid>>3)&3
                        : ((tid & 3) << 4);
  auto aload = [&](int kt) {
    const float* A = (const float*)Av;
    const float* g0 = A + (size_t)(bm0 + arow)*K + kt*32 + ac0;
    const float* g1 = A + (size_t)(bm0 + 64 + arow)*K + kt*32 + ac0;
    L0 = *(const f32x4*)g0; L1 = *(const f32x4*)(g0 + 4);
    L2 = *(const f32x4*)g1; L3 = *(const f32x4*)(g1 + 4);
  };
  auto awrite = [&](int bb) {
    half8 h0, h1;
#pragma unroll
    for (int j = 0; j < 4; ++j) { h0[j] = (half_t)L0[j]; h0[j+4] = (half_t)L1[j]; }
#pragma unroll
    for (int j = 0; j < 4; ++j) { h1[j] = (half_t)L2[j]; h1[j+4] = (half_t)L3[j]; }
    *(half8*)((char*)As[bb] + (size_t)arow*64 + wslot)        = h0;
    *(half8*)((char*)As[bb] + (size_t)(64 + arow)*64 + wslot) = h1;
  };

  auto compute = [&](int ab, int bb) {
    half8 af[4], bf[4];
#pragma unroll
    for (int m = 0; m < 4; ++m)
      af[m] = *(const half8*)((const char*)As[ab] + (size_t)(wr*64 + m*16 + l4)*64 + rslot);
#pragma unroll
    for (int n = 0; n < 4; ++n)
      bf[n] = *(const half8*)((const char*)Bs[bb] + (size_t)(wc*64 + n*16 + l4)*64 + rslot);
#pragma unroll
    for (int m = 0; m < 4; ++m)
#pragma unroll
      for (int n = 0; n < 4; ++n)
        acc[m][n] = __builtin_amdgcn_mfma_f32_16x16x32_f16(af[m], bf[n], acc[m][n], 0, 0, 0);
  };

  if constexpr (!AF32) {
    // ---- prologue: A tiles 0,1 + B tile 0; one-time full drain ----
    stageA16(0, 0); stageA16(1, 1); stageB(0, 0);
    asm volatile("s_waitcnt vmcnt(0)" ::: "memory");
    BAR();
    int aCur = 0, aP2 = 2;                       // t%3, (t+2)%3
    for (int t = 0; t < nk; ++t) {
      if (t + 1 < nk) stageB(t + 1, (t + 1) & 1);   // B first (older in queue)
      if (t + 2 < nk) stageA16(t + 2, aP2);         // A second (left in flight)
      compute(aCur, t & 1);
      if (t + 1 < nk) {
        if (t + 2 < nk) { asm volatile("s_waitcnt vmcnt(2)" ::: "memory"); }
        else            { asm volatile("s_waitcnt vmcnt(0)" ::: "memory"); }
        BAR();
      }
      aCur = (aCur == 2) ? 0 : aCur + 1;
      aP2  = (aP2  == 2) ? 0 : aP2  + 1;
    }
  } else {
    // ---- prologue ----
    aload(0); stageB(0, 0); stageB(1, 1);
    awrite(0);                                   // implicit wait on the 4 A-loads
    asm volatile("s_waitcnt vmcnt(2) lgkmcnt(0)" ::: "memory");  // B0 landed, B1 flying
    BAR();
    int bCur = 0, bP2 = 2;                       // t%3, (t+2)%3
    for (int t = 0; t < nk; ++t) {
      if (t + 1 < nk) aload(t + 1);              // issue early (T14)
      if (t + 2 < nk) stageB(t + 2, bP2);
      compute(t & 1, bCur);
      if (t + 1 < nk) {
        awrite((t + 1) & 1);                     // cvt+ds_write; implicitly forces B(t+1) landed
        asm volatile("s_waitcnt lgkmcnt(0)" ::: "memory");
        BAR();
      }
      bCur = (bCur == 2) ? 0 : bCur + 1;
      bP2  = (bP2  == 2) ? 0 : bP2  + 1;
    }
  }

  // ---- epilogue: row = bm0+wr*64+m*16+lh*4+j, col = bn0+wc*64+n*16+l4 ----
  const int c_base = bn0 + wc*64;
  const int r_base = bm0 + wr*64;
#pragma unroll
  for (int n = 0; n < 4; ++n) {
    const int col = c_base + n*16 + l4;
    const float bvv = bias[col];
#pragma unroll
    for (int m = 0; m < 4; ++m) {
#pragma unroll
      for (int j = 0; j < 4; ++j) {
        const int row = r_base + m*16 + lh*4 + j;
        const float v = acc[m][n][j] + bvv;
        if constexpr (OUTF32) {
          ((float*)Cv)[(size_t)row*N + col] = v;
        } else if constexpr (SWZ) {
          size_t byte = ((size_t)row*N + col)*2;
          byte ^= ((size_t)((row >> 1) & 3)) << 4;       // store q pre-swizzled
          *(half_t*)((char*)Cv + byte) = (half_t)v;
        } else {
          ((half_t*)Cv)[(size_t)row*N + col] = (half_t)v;
        }
      }
    }
  }
}

// ---------------- attention ----------------
// q is SWIZZLED fp16 (XOR byte[5:4] with (row>>1)&3); kv plain. (Verified R3-R5.)
__global__ __launch_bounds__(256, 2)
void attn_kernel(half_t* __restrict__ q, const half_t* __restrict__ kv) {
  __shared__ half_t K_lds[80*136];
  __shared__ half_t Vt_lds[128*104];
  __shared__ half_t P_lds[64*104];
  const int tid = threadIdx.x;
  const int l = tid & 63, w = tid >> 6;
  const int l4 = l & 15, lh = l >> 4;
  const int bh = blockIdx.y;
  const int b = bh >> 3, h = bh & 7;
  const size_t kvbase = (size_t)b*SEQ_KV*2048 + (size_t)h*D_HEAD;

  for (int i = tid; i < 80*16; i += 256) {
    int s = i >> 4, d = (i & 15) << 3;
    half8 v = {};
    if (s < SEQ_KV) v = *(const half8*)(kv + kvbase + (size_t)s*2048 + d);
    *(half8*)(K_lds + s*136 + d) = v;
  }
  for (int i = tid; i < 96*16; i += 256) {
    int s = i >> 4, d = (i & 15) << 3;
    half8 v = {};
    if (s < SEQ_KV) v = *(const half8*)(kv + kvbase + (size_t)s*2048 + 1024 + d);
#pragma unroll
    for (int j = 0; j < 8; ++j) Vt_lds[(size_t)(d + j)*104 + s] = v[j];
  }
  {
    int rr = tid >> 2, cc = 80 + (tid & 3)*4;
    *reinterpret_cast<uint2*>(P_lds + (size_t)rr*104 + cc) = make_uint2(0u, 0u);
  }
  __syncthreads();

  const int qrow0 = blockIdx.x*64 + w*16;
  const size_t qrow = (size_t)b*SEQ_Q + qrow0 + l4;
  const size_t rowbyte = qrow*2048;
  const size_t rkey = ((size_t)((l4 >> 1) & 3)) << 4;   // (qrow>>1)&3 == (l4>>1)&3
  half8 qf[4];
#pragma unroll
  for (int kk = 0; kk < 4; ++kk) {
    size_t byte = rowbyte + (size_t)h*256 + kk*64 + lh*16;
    qf[kk] = *(const half8*)((const char*)q + (byte ^ rkey));
  }

  f32x4 sa[5] = {};
#pragma unroll
  for (int nb = 0; nb < 5; ++nb)
#pragma unroll
    for (int kk = 0; kk < 4; ++kk) {
      half8 kf = *(const half8*)(K_lds + (size_t)(nb*16 + l4)*136 + kk*32 + lh*8);
      sa[nb] = __builtin_amdgcn_mfma_f32_16x16x32_f16(qf[kk], kf, sa[nb], 0, 0, 0);
    }

  const float scale = 0.08838834764831845f;
#pragma unroll
  for (int j = 0; j < 4; ++j) {
    float pv[5];
    float mx = -1e30f;
#pragma unroll
    for (int nb = 0; nb < 5; ++nb) {
      int col = nb*16 + l4;
      float sv = (col < SEQ_KV) ? sa[nb][j]*scale : -1e30f;
      pv[nb] = sv;
      mx = fmaxf(mx, sv);
    }
    mx = fmaxf(mx, __shfl_xor(mx, 1));
    mx = fmaxf(mx, __shfl_xor(mx, 2));
    mx = fmaxf(mx, __shfl_xor(mx, 4));
    mx = fmaxf(mx, __shfl_xor(mx, 8));
    float sm = 0.f;
#pragma unroll
    for (int nb = 0; nb < 5; ++nb) { float e = __expf(pv[nb] - mx); pv[nb] = e; sm += e; }
    sm += __shfl_xor(sm, 1);
    sm += __shfl_xor(sm, 2);
    sm += __shfl_xor(sm, 4);
    sm += __shfl_xor(sm, 8);
    const float inv = 1.f / sm;
    const int prow = w*16 + lh*4 + j;
#pragma unroll
    for (int nb = 0; nb < 5; ++nb)
      P_lds[(size_t)prow*104 + nb*16 + l4] = (half_t)(pv[nb]*inv);
  }

  half8 pf[3];
#pragma unroll
  for (int kk = 0; kk < 3; ++kk)
    pf[kk] = *(const half8*)(P_lds + (size_t)(w*16 + l4)*104 + kk*32 + lh*8);
  f32x4 oa[8] = {};
#pragma unroll
  for (int nd = 0; nd < 8; ++nd)
#pragma unroll
    for (int kk = 0; kk < 3; ++kk) {
      half8 vf = *(const half8*)(Vt_lds + (size_t)(nd*16 + l4)*104 + kk*32 + lh*8);
      oa[nd] = __builtin_amdgcn_mfma_f32_16x16x32_f16(pf[kk], vf, oa[nd], 0, 0, 0);
    }
  // write O in place, swizzled
#pragma unroll
  for (int nd = 0; nd < 8; ++nd) {
#pragma unroll
    for (int j = 0; j < 4; ++j) {
      const int rl = lh*4 + j;
      const size_t row = (size_t)b*SEQ_Q + qrow0 + rl;
      size_t byte = row*2048 + (size_t)h*256 + (size_t)(nd*16 + l4)*2;
      byte ^= ((size_t)((rl >> 1) & 3)) << 4;
      *(half_t*)((char*)q + byte) = (half_t)oa[nd][j];
    }
  }
}

// ---------------- launch ----------------
extern "C" void kernel_launch(void* const* d_in, const int* in_sizes, int n_in,
                              void* d_out, int out_size, void* d_ws, size_t ws_size,
                              hipStream_t stream) {
  (void)in_sizes; (void)n_in; (void)out_size; (void)ws_size;
  const float* x  = (const float*)d_in[0];
  const float* y  = (const float*)d_in[1];
  const float* Wq = (const float*)d_in[2];
  const float* bq = (const float*)d_in[3];
  const float* Wk = (const float*)d_in[4];
  const float* bk = (const float*)d_in[5];
  const float* Wv = (const float*)d_in[6];
  const float* bv = (const float*)d_in[7];
  const float* Wo = (const float*)d_in[8];
  const float* bo = (const float*)d_in[9];

  char* ws = (char*)d_ws;
  half_t* q    = (half_t*)(ws + WS_Q);
  half_t* Wqt  = (half_t*)(ws + WS_WQT);
  half_t* Wot  = (half_t*)(ws + WS_WOT);
  half_t* Wkvt = (half_t*)(ws + WS_WKVT);
  half_t* yh   = (half_t*)(ws + WS_YH);
  half_t* kvb  = (half_t*)(ws + WS_KV);
  float*  bkv  = (float*)(ws + WS_BKV);

  dim3 tb(32, 8);
  transpose_f32f16<true ><<<dim3(32, 32), tb, 0, stream>>>(Wq, Wqt, 1024, 1024);
  transpose_f32f16<true ><<<dim3(32, 32), tb, 0, stream>>>(Wo, Wot, 1024, 1024);
  transpose_f32f16<false><<<dim3(32, 24), tb, 0, stream>>>(Wk, Wkvt, 768, 1024);
  transpose_f32f16<false><<<dim3(32, 24), tb, 0, stream>>>(Wv, Wkvt + (size_t)1024*768, 768, 1024);
  convert_pad_y<<<ROWS_KV_PAD*D_CROSS/256, 256, 0, stream>>>(y, yh);
  concat_bias<<<2*D_EMBED/256, 256, 0, stream>>>(bk, bv, bkv);

  // K/V projection: [640,768] @ [768,2048] (plain layouts, same pipelined template)
  gemm_f16<false, false, false><<<dim3(16, 5), 256, 0, stream>>>(yh, Wkvt, bkv, kvb, ROWS_KV_PAD, 2048, 768);
  // Q projection: fp32 A reg-staged (T14), counted-vmcnt pipeline -> q (swizzled fp16)
  gemm_f16<true, false, true><<<dim3(8, 256), 256, 0, stream>>>(x, Wqt, bq, q, M_Q, 1024, 1024);
  // attention (in-place over swizzled q)
  attn_kernel<<<dim3(64, 64), 256, 0, stream>>>(q, kvb);
  // O projection: fp16 A (swizzled q), A 2-ahead / B 1-ahead counted-vmcnt -> fp32 d_out
  gemm_f16<false, true, true><<<dim3(8, 256), 256, 0, stream>>>(q, Wot, bo, (float*)d_out, M_Q, 1024, 1024);
}